// Round 1
// baseline (383.210 us; speedup 1.0000x reference)
//
#include <hip/hip_runtime.h>
#include <math.h>

#define B_DIM 16
#define C_DIM 256
#define L_DIM 8192
#define D_INNER 512
#define ATT 64
#define NK 11   // power sums S_1..S_11 (Taylor order K=10)

// Single fused kernel. Block = (b, 128-l tile); 1024 blocks x 256 threads.
// Phase 0: per-block weight prep (qk scalar + wo_v[512] into LDS) - L1/L2
//          served, overlaps with the h_v stream.
// Phase 1: power sums S_1..S_11 over the 256 channels (4 c-groups x 64
//          float2 l-lanes), LDS combine, closed-form Taylor softmax-pool
//          -> pooled_s[128] in LDS.
// Phase 2: rank-1 expansion out[b, d, ltile] = pooled_s[l] * wo_s[d],
//          256 KiB coalesced float4 stores per block.
__global__ __launch_bounds__(256) void fused_kernel(
    const float* __restrict__ h_v, const float* __restrict__ wq,
    const float* __restrict__ wk, const float* __restrict__ wv,
    const float* __restrict__ w_out, float* __restrict__ out) {
    __shared__ float2 red[4][64][NK];          // 22528 B
    __shared__ float  wo_s[D_INNER];           //  2048 B
    __shared__ __align__(16) float2 pooled_s[64];  // 512 B

    const int t    = threadIdx.x;
    const int cg   = t >> 6;          // 0..3
    const int lane = t & 63;          // l-lane (float2) within 128-l tile
    const int b    = blockIdx.x >> 6; // 64 tiles per b
    const int lt   = blockIdx.x & 63;

    // ---- Phase 0: per-block weight prep (same accumulation order as the
    // old prep_kernel -> bitwise-identical results). wq/wk/wv are uniform
    // addresses (scalar loads); w_out rows for this wave live in a 16 KiB
    // slab -> L1-resident after the first iteration.
    {
        float a0 = 0.f, a1 = 0.f;
        #pragma unroll
        for (int a = 0; a < ATT; ++a) {
            float w = wv[a];
            a0 += w_out[t * ATT + a] * w;
            a1 += w_out[(t + 256) * ATT + a] * w;
        }
        wo_s[t]       = a0;
        wo_s[t + 256] = a1;
    }
    float qs = 0.f;
    #pragma unroll
    for (int a = 0; a < ATT; ++a) qs += wq[a] * wk[a];
    qs *= 0.125f;  // 1/sqrt(64)

    // ---- Phase 1: power sums over this thread's 64 channels.
    const float* src = h_v + (size_t)b * (C_DIM * L_DIM) + lt * 128 + lane * 2
                           + (size_t)cg * 64 * L_DIM;

    float2 S[NK];
    #pragma unroll
    for (int j = 0; j < NK; ++j) S[j] = make_float2(0.f, 0.f);

    #pragma unroll 4
    for (int c = 0; c < 64; ++c) {
        float2 v = *(const float2*)(src + (size_t)c * L_DIM);
        float px = v.x, py = v.y;
        S[0].x += px; S[0].y += py;
        #pragma unroll
        for (int j = 1; j < NK; ++j) {
            px *= v.x; py *= v.y;
            S[j].x += px; S[j].y += py;
        }
    }
    #pragma unroll
    for (int j = 0; j < NK; ++j) red[cg][lane][j] = S[j];
    __syncthreads();

    if (cg == 0) {
        #pragma unroll
        for (int g = 1; g < 4; ++g) {
            #pragma unroll
            for (int j = 0; j < NK; ++j) {
                float2 a = red[g][lane][j];
                S[j].x += a.x; S[j].y += a.y;
            }
        }
        const float t0 = S[0].x * (1.0f / C_DIM) * qs;
        const float t1 = S[0].y * (1.0f / C_DIM) * qs;

        const float invfact[NK] = {
            1.f, 1.f, 0.5f, 1.f/6.f, 1.f/24.f, 1.f/120.f, 1.f/720.f,
            1.f/5040.f, 1.f/40320.f, 1.f/362880.f, 1.f/3628800.f};

        float den0 = (float)C_DIM, num0 = S[0].x;
        float den1 = (float)C_DIM, num1 = S[0].y;
        float tp0 = 1.f, tp1 = 1.f;
        #pragma unroll
        for (int k = 1; k <= 10; ++k) {
            tp0 *= t0; tp1 *= t1;
            float c0 = tp0 * invfact[k];
            float c1 = tp1 * invfact[k];
            den0 += c0 * S[k - 1].x;  num0 += c0 * S[k].x;
            den1 += c1 * S[k - 1].y;  num1 += c1 * S[k].y;
        }
        float2 o;
        o.x = num0 / den0;
        o.y = num1 / den1;
        pooled_s[lane] = o;
    }
    __syncthreads();

    // ---- Phase 2: rank-1 expansion. Wave lanes 0-31 / 32-63 each cover one
    // full 512 B row segment -> coalesced dwordx4 store streams.
    const int jj = t & 31;   // float4 column within the 128-l tile
    const int d0 = t >> 5;   // 0..7, d stride 8
    const float4 p = ((const float4*)pooled_s)[jj];
    float* dst = out + ((size_t)b * D_INNER + d0) * L_DIM + lt * 128 + jj * 4;
    #pragma unroll 8
    for (int d = d0; d < D_INNER; d += 8) {
        float w = wo_s[d];
        float4 o4;
        o4.x = p.x * w; o4.y = p.y * w; o4.z = p.z * w; o4.w = p.w * w;
        *(float4*)dst = o4;
        dst += 8 * (size_t)L_DIM;
    }
}

extern "C" void kernel_launch(void* const* d_in, const int* in_sizes, int n_in,
                              void* d_out, int out_size, void* d_ws, size_t ws_size,
                              hipStream_t stream) {
    const float* h_v   = (const float*)d_in[0];
    const float* wq    = (const float*)d_in[1];
    const float* wk    = (const float*)d_in[2];
    const float* wv    = (const float*)d_in[3];
    const float* w_out = (const float*)d_in[4];
    float* out = (float*)d_out;

    // B * (L/128) = 1024 blocks
    hipLaunchKernelGGL(fused_kernel, dim3(1024), dim3(256), 0, stream,
                       h_v, wq, wk, wv, w_out, out);
}

// Round 2
// 377.373 us; speedup vs baseline: 1.0155x; 1.0155x over previous
//
#include <hip/hip_runtime.h>
#include <math.h>

#define B_DIM 16
#define C_DIM 256
#define L_DIM 8192
#define D_INNER 512
#define ATT 64
#define NK 11   // power sums S_1..S_11 (Taylor order K=10)

typedef float vf4 __attribute__((ext_vector_type(4)));

static __device__ __forceinline__ vf4 splat4(float s) {
    vf4 v = {s, s, s, s};
    return v;
}

// ws layout (floats):
//   [0]                qk_scale = <wq,wk>/sqrt(64)
//   [64 .. 64+512)     wo_v[d] = sum_a w_out[d][a]*wv[a]
//   [1024 .. 1024+B*L) pooled[b][l]

__global__ __launch_bounds__(512) void prep_kernel(
    const float* __restrict__ wq, const float* __restrict__ wk,
    const float* __restrict__ wv, const float* __restrict__ w_out,
    float* __restrict__ ws) {
    int d = threadIdx.x;  // 0..511
    float acc = 0.f;
    #pragma unroll
    for (int a = 0; a < ATT; ++a) acc += w_out[d * ATT + a] * wv[a];
    ws[64 + d] = acc;
    if (d == 0) {
        float qk = 0.f;
        #pragma unroll
        for (int a = 0; a < ATT; ++a) qk += wq[a] * wk[a];
        ws[0] = qk * 0.125f;  // 1/sqrt(64)
    }
}

// Single pass over h_v. Block = (b, 256-l tile); threads = 4 c-groups x 64
// l-lanes (float4/lane -> 1 KB contiguous per wave request). Each thread
// accumulates power sums S_1..S_11 of its 64 c values; LDS-combine across
// c-groups; evaluate Taylor series of softmax-pool; write pooled[b,l].
//   den = sum_c exp(t*h) = sum_k t^k/k! S_k   (S_0 = 256)
//   num = sum_c h*exp(t*h) = sum_k t^k/k! S_{k+1}
__global__ __launch_bounds__(256) void pooled_kernel(
    const float* __restrict__ h_v, const float* __restrict__ ws,
    float* __restrict__ pooled) {
    __shared__ vf4 red[4][64][NK];  // 44 KB

    const int t    = threadIdx.x;
    const int cg   = t >> 6;          // 0..3
    const int lane = t & 63;          // l-lane (float4) within 256-l tile
    const int b    = blockIdx.x >> 5; // 32 tiles per b
    const int lt   = blockIdx.x & 31;

    const float* src = h_v + (size_t)b * (C_DIM * L_DIM) + lt * 256 + lane * 4
                           + (size_t)cg * 64 * L_DIM;

    vf4 S[NK];
    #pragma unroll
    for (int j = 0; j < NK; ++j) S[j] = splat4(0.f);

    #pragma unroll 4
    for (int c = 0; c < 64; ++c) {
        vf4 v = __builtin_nontemporal_load(
            (const vf4*)(src + (size_t)c * L_DIM));
        vf4 p = v;
        S[0] += v;
        #pragma unroll
        for (int j = 1; j < NK; ++j) {
            p *= v;
            S[j] += p;
        }
    }
    #pragma unroll
    for (int j = 0; j < NK; ++j) red[cg][lane][j] = S[j];
    __syncthreads();

    if (cg == 0) {
        #pragma unroll
        for (int g = 1; g < 4; ++g) {
            #pragma unroll
            for (int j = 0; j < NK; ++j) S[j] += red[g][lane][j];
        }
        const float qs = ws[0];
        const vf4 tt = S[0] * (1.0f / C_DIM) * qs;

        const float invfact[NK] = {
            1.f, 1.f, 0.5f, 1.f/6.f, 1.f/24.f, 1.f/120.f, 1.f/720.f,
            1.f/5040.f, 1.f/40320.f, 1.f/362880.f, 1.f/3628800.f};

        vf4 den = splat4((float)C_DIM);
        vf4 num = S[0];
        vf4 tp  = splat4(1.f);
        #pragma unroll
        for (int k = 1; k <= 10; ++k) {
            tp *= tt;
            vf4 c = tp * invfact[k];
            den += c * S[k - 1];
            num += c * S[k];
        }
        vf4 o = num / den;
        ((vf4*)(pooled + (size_t)b * L_DIM + lt * 256))[lane] = o;
    }
}

// out[b,d,l] = pooled[b,l] * wo_v[d]. Grid-stride: 4096 blocks x 16 float4
// iterations; at any instant the GPU sweeps one contiguous ~16 MB window.
#define TOTAL4 (B_DIM * D_INNER * (L_DIM / 4))  // 16777216 float4 stores
#define WGRID 4096

__global__ __launch_bounds__(256) void write_kernel(
    const float* __restrict__ ws, float* __restrict__ out) {
    const float* wo_v   = ws + 64;
    const float* pooled = ws + 1024;
    int i = blockIdx.x * 256 + threadIdx.x;  // float4 index
    #pragma unroll 1
    for (; i < TOTAL4; i += WGRID * 256) {
        int l4  = i & 2047;                  // L/4 = 2048
        int tmp = i >> 11;
        int d   = tmp & 511;
        int b   = tmp >> 9;
        vf4 p = ((const vf4*)(pooled + (size_t)b * L_DIM))[l4];
        float w = wo_v[d];
        vf4 o = p * w;
        __builtin_nontemporal_store(o, ((vf4*)out) + i);
    }
}

extern "C" void kernel_launch(void* const* d_in, const int* in_sizes, int n_in,
                              void* d_out, int out_size, void* d_ws, size_t ws_size,
                              hipStream_t stream) {
    const float* h_v   = (const float*)d_in[0];
    const float* wq    = (const float*)d_in[1];
    const float* wk    = (const float*)d_in[2];
    const float* wv    = (const float*)d_in[3];
    const float* w_out = (const float*)d_in[4];
    float* ws  = (float*)d_ws;
    float* out = (float*)d_out;

    hipLaunchKernelGGL(prep_kernel, dim3(1), dim3(512), 0, stream,
                       wq, wk, wv, w_out, ws);
    // B * (L/256) = 512 blocks
    hipLaunchKernelGGL(pooled_kernel, dim3(512), dim3(256), 0, stream,
                       h_v, ws, ws + 1024);
    hipLaunchKernelGGL(write_kernel, dim3(WGRID), dim3(256), 0, stream,
                       ws, out);
}

// Round 3
// 356.951 us; speedup vs baseline: 1.0736x; 1.0572x over previous
//
#include <hip/hip_runtime.h>
#include <math.h>

#define B_DIM 16
#define C_DIM 256
#define L_DIM 8192
#define D_INNER 512
#define ATT 64
#define NK 11   // power sums S_1..S_11 (Taylor order K=10)

typedef float vf4 __attribute__((ext_vector_type(4)));

static __device__ __forceinline__ vf4 splat4(float s) {
    vf4 v = {s, s, s, s};
    return v;
}

// ws layout (floats):
//   [64 .. 64+512)     wo_v[d] = sum_a w_out[d][a]*wv[a]   (written by block 0)
//   [1024 .. 1024+B*L) pooled[b][l]

// Single pass over h_v, prep fused in. Block = (b, 256-l tile); threads =
// 4 c-groups x 64 l-lanes (float4/lane -> 1 KB contiguous per wave request).
// Each thread accumulates power sums S_1..S_11 of its 64 c values; LDS-combine
// across c-groups; evaluate the Taylor series of the softmax-pool in closed
// form; write pooled[b,l].
//   den = sum_c exp(t*h) = sum_k t^k/k! S_k   (S_0 = 256)
//   num = sum_c h*exp(t*h) = sum_k t^k/k! S_{k+1}
// Block 0 additionally computes wo_v[512] into ws (consumed only by the next
// dispatch -> ordering guaranteed by the dispatch boundary).
__global__ __launch_bounds__(256) void pooled_kernel(
    const float* __restrict__ h_v, const float* __restrict__ wq,
    const float* __restrict__ wk, const float* __restrict__ wv,
    const float* __restrict__ w_out, float* __restrict__ ws) {
    __shared__ vf4 red[4][64][NK];  // 44 KB

    const int t    = threadIdx.x;
    const int cg   = t >> 6;          // 0..3
    const int lane = t & 63;          // l-lane (float4) within 256-l tile
    const int b    = blockIdx.x >> 5; // 32 tiles per b
    const int lt   = blockIdx.x & 31;

    // ---- fused prep: block 0 computes wo_v (same accumulation order as the
    // old prep_kernel -> bitwise-identical).
    if (blockIdx.x == 0) {
        float a0 = 0.f, a1 = 0.f;
        #pragma unroll
        for (int a = 0; a < ATT; ++a) {
            float w = wv[a];
            a0 += w_out[t * ATT + a] * w;
            a1 += w_out[(t + 256) * ATT + a] * w;
        }
        ws[64 + t]       = a0;
        ws[64 + t + 256] = a1;
    }
    // qk scale, computed per block (uniform scalar loads, ~free).
    float qs = 0.f;
    #pragma unroll
    for (int a = 0; a < ATT; ++a) qs += wq[a] * wk[a];
    qs *= 0.125f;  // 1/sqrt(64)

    const float* src = h_v + (size_t)b * (C_DIM * L_DIM) + lt * 256 + lane * 4
                           + (size_t)cg * 64 * L_DIM;

    vf4 S[NK];
    #pragma unroll
    for (int j = 0; j < NK; ++j) S[j] = splat4(0.f);

    #pragma unroll 4
    for (int c = 0; c < 64; ++c) {
        vf4 v = *(const vf4*)(src + (size_t)c * L_DIM);
        vf4 p = v;
        S[0] += v;
        #pragma unroll
        for (int j = 1; j < NK; ++j) {
            p *= v;
            S[j] += p;
        }
    }
    #pragma unroll
    for (int j = 0; j < NK; ++j) red[cg][lane][j] = S[j];
    __syncthreads();

    if (cg == 0) {
        #pragma unroll
        for (int g = 1; g < 4; ++g) {
            #pragma unroll
            for (int j = 0; j < NK; ++j) S[j] += red[g][lane][j];
        }
        const vf4 tt = S[0] * (1.0f / C_DIM) * qs;

        const float invfact[NK] = {
            1.f, 1.f, 0.5f, 1.f/6.f, 1.f/24.f, 1.f/120.f, 1.f/720.f,
            1.f/5040.f, 1.f/40320.f, 1.f/362880.f, 1.f/3628800.f};

        vf4 den = splat4((float)C_DIM);
        vf4 num = S[0];
        vf4 tp  = splat4(1.f);
        #pragma unroll
        for (int k = 1; k <= 10; ++k) {
            tp *= tt;
            vf4 c = tp * invfact[k];
            den += c * S[k - 1];
            num += c * S[k];
        }
        vf4 o = num / den;
        ((vf4*)(ws + 1024 + (size_t)b * L_DIM + lt * 256))[lane] = o;
    }
}

// out[b,d,l] = pooled[b,l] * wo_v[d]; one float4 per thread, pure stream
// write in output-linear order (consecutive blocks -> consecutive 4 KB).
__global__ __launch_bounds__(256) void write_kernel(
    const float* __restrict__ ws, float* __restrict__ out) {
    const float* wo_v   = ws + 64;
    const float* pooled = ws + 1024;
    int i   = blockIdx.x * 256 + threadIdx.x;  // float4 index
    int l4  = i & 2047;                        // L/4 = 2048
    int tmp = i >> 11;
    int d   = tmp & 511;
    int b   = tmp >> 9;
    vf4 p  = ((const vf4*)(pooled + (size_t)b * L_DIM))[l4];
    float w = wo_v[d];
    vf4 o = p * w;
    __builtin_nontemporal_store(o, ((vf4*)out) + i);
}

extern "C" void kernel_launch(void* const* d_in, const int* in_sizes, int n_in,
                              void* d_out, int out_size, void* d_ws, size_t ws_size,
                              hipStream_t stream) {
    const float* h_v   = (const float*)d_in[0];
    const float* wq    = (const float*)d_in[1];
    const float* wk    = (const float*)d_in[2];
    const float* wv    = (const float*)d_in[3];
    const float* w_out = (const float*)d_in[4];
    float* ws  = (float*)d_ws;
    float* out = (float*)d_out;

    // B * (L/256) = 512 blocks
    hipLaunchKernelGGL(pooled_kernel, dim3(512), dim3(256), 0, stream,
                       h_v, wq, wk, wv, w_out, ws);
    // B*D*L/4 = 16777216 float4 stores
    hipLaunchKernelGGL(write_kernel, dim3(65536), dim3(256), 0, stream,
                       ws, out);
}